// Round 12
// baseline (398.250 us; speedup 1.0000x reference)
//
#include <hip/hip_runtime.h>

// WECT R11 = R10 with the nontemporal-load type fixed (int2 -> long long).
// R9/R10 theory: non-atomic LDS RMW, GD=16, quad shfl-dedupe, 8 waves/CU;
// U=4 batches (16 gathers in flight/wave) to amortize gather latency;
// nontemporal edge/tri stream loads protect the per-XCD L2 table.

#define HGT 256
#define NDIR 64
#define NBINS (HGT * NDIR)
#define NG 4
#define GD 16
#define PADH 257
#define WH (GD * PADH)  // 4112 floats per wave
#define TPB 256
#define NWV (TPB / 64)
#define VSL 128
#define SSL 128
#define UE 4
#define UT 4
#define UV 4

__global__ void wect_maxnorm(const float* __restrict__ vc, int k0,
                             unsigned* __restrict__ maxbits) {
    float m = 0.f;
    for (int i = blockIdx.x * blockDim.x + threadIdx.x; i < k0;
         i += gridDim.x * blockDim.x) {
        float x = vc[3 * i], y = vc[3 * i + 1], z = vc[3 * i + 2];
        m = fmaxf(m, sqrtf(x * x + y * y + z * z));
    }
    for (int off = 32; off > 0; off >>= 1)
        m = fmaxf(m, __shfl_down(m, off, 64));
    __shared__ float sm[16];
    int wid = threadIdx.x >> 6, lane = threadIdx.x & 63;
    if (lane == 0) sm[wid] = m;
    __syncthreads();
    if (threadIdx.x == 0) {
        float b = sm[0];
        int nw = blockDim.x >> 6;
        for (int w = 1; w < nw; ++w) b = fmaxf(b, sm[w]);
        atomicMax(maxbits, __float_as_uint(b));  // valid: all values >= 0
    }
}

__device__ __forceinline__ int height_bin(float h, float mh, float inv) {
    int idx = (int)ceilf((255.0f * (mh + h)) * inv);
    return min(max(idx, 0), HGT - 1);
}

// Merge same-address lanes within the xor-quad {l, l^16, l^32, l^48}.
// All 6 pairs covered by masks 16,32,48. Upper lane of a matching pair
// donates w and retargets the (harmless, unread) pad column.
__device__ __forceinline__ void dedupe4(int& a, float& w, int lane, int pad) {
#pragma unroll
    for (int m = 16; m <= 48; m += 16) {
        int pa = __shfl_xor(a, m, 64);
        float pw = __shfl_xor(w, m, 64);
        bool match = (pa == a);
        bool upper = lane > (lane ^ m);
        if (match) {
            if (upper) {
                w = 0.f;
                a = pad;
            } else {
                w += pw;
            }
        }
    }
}

__device__ __forceinline__ void flush4(const float* hist, int g,
                                       float* __restrict__ out) {
    for (int t = threadIdx.x; t < GD * HGT; t += TPB) {
        int d = t >> 8, b = t & 255;
        float s = 0.f;
#pragma unroll
        for (int u = 0; u < NWV; ++u) s += hist[u * WH + d * PADH + b];
        if (s != 0.f) atomicAdd(&out[(g * GD + d) * HGT + b], s);
    }
}

__global__ __launch_bounds__(TPB) void wect_vertex4(
    const float* __restrict__ vc, const float* __restrict__ vw,
    const float* __restrict__ dirs, int k0,
    const unsigned* __restrict__ maxbits, unsigned char* __restrict__ tab,
    float* __restrict__ out) {
    __shared__ float hist[NWV * WH];
    int tid = threadIdx.x, lane = tid & 63, wv = tid >> 6;
    int dl = lane & 15, sub = lane >> 4;
    for (int t = tid; t < NWV * WH; t += TPB) hist[t] = 0.f;
    int g = blockIdx.x & (NG - 1);
    int slice = blockIdx.x >> 2;
    int gd = g * GD + dl;
    float dx = dirs[3 * gd], dy = dirs[3 * gd + 1], dz = dirs[3 * gd + 2];
    float mh = __uint_as_float(*maxbits);
    float inv = 1.0f / (2.0f * mh);
    unsigned char* tabg = tab + (size_t)g * k0 * GD;
    float* H = hist + wv * WH;
    int pad = dl * PADH + 256;
    __syncthreads();
    int lo = (int)((long long)k0 * slice / VSL);
    int hi = (int)((long long)k0 * (slice + 1) / VSL);
    for (int s0 = lo + wv * 4 * UV; s0 < hi; s0 += NWV * 4 * UV) {
        int a_[UV];
        float w_[UV];
#pragma unroll
        for (int u = 0; u < UV; ++u) {
            int s = min(s0 + u * 4 + sub, hi - 1);
            bool act = (s0 + u * 4 + sub) < hi;
            float x = vc[3 * s], y = vc[3 * s + 1], z = vc[3 * s + 2];
            float w = act ? vw[s] : 0.f;
            float h = fmaf(x, dx, fmaf(y, dy, z * dz));
            int b = height_bin(h, mh, inv);
            if (act) tabg[(size_t)s * GD + dl] = (unsigned char)b;
            a_[u] = dl * PADH + b;
            w_[u] = w;
        }
#pragma unroll
        for (int u = 0; u < UV; ++u) {
            dedupe4(a_[u], w_[u], lane, pad);
            float v = H[a_[u]];
            H[a_[u]] = v + w_[u];
        }
    }
    __syncthreads();
    flush4(hist, g, out);
}

__global__ __launch_bounds__(TPB) void wect_simplex4(
    const long long* __restrict__ edges, const float* __restrict__ ew,
    const int* __restrict__ tris, const float* __restrict__ tw, int k1, int k2,
    const unsigned char* __restrict__ tab, int k0, float* __restrict__ out) {
    __shared__ float hist[NWV * WH];
    int tid = threadIdx.x, lane = tid & 63, wv = tid >> 6;
    int dl = lane & 15, sub = lane >> 4;
    for (int t = tid; t < NWV * WH; t += TPB) hist[t] = 0.f;
    int g = blockIdx.x & (NG - 1);
    int slice = blockIdx.x >> 2;
    const unsigned char* tabg = tab + (size_t)g * k0 * GD;
    float* H = hist + wv * WH;
    int pad = dl * PADH + 256;
    __syncthreads();

    // ---- edges: +w, max over 2 endpoints ----
    {
        int lo = (int)((long long)k1 * slice / SSL);
        int hi = (int)((long long)k1 * (slice + 1) / SSL);
        for (int s0 = lo + wv * 4 * UE; s0 < hi; s0 += NWV * 4 * UE) {
            int a_[UE];
            float w_[UE];
#pragma unroll
            for (int u = 0; u < UE; ++u) {
                int s = min(s0 + u * 4 + sub, hi - 1);
                bool act = (s0 + u * 4 + sub) < hi;
                long long ep = __builtin_nontemporal_load(edges + s);
                float w = act ? __builtin_nontemporal_load(ew + s) : 0.f;
                int ex = (int)(ep & 0xffffffffLL);
                int ey = (int)(ep >> 32);
                int A = tabg[(size_t)ex * GD + dl];
                int B = tabg[(size_t)ey * GD + dl];
                a_[u] = dl * PADH + max(A, B);
                w_[u] = w;
            }
#pragma unroll
            for (int u = 0; u < UE; ++u) {
                dedupe4(a_[u], w_[u], lane, pad);
                float v = H[a_[u]];
                H[a_[u]] = v + w_[u];
            }
        }
    }

    // ---- triangles: -w, max over 3 endpoints ----
    {
        int lo = (int)((long long)k2 * slice / SSL);
        int hi = (int)((long long)k2 * (slice + 1) / SSL);
        for (int s0 = lo + wv * 4 * UT; s0 < hi; s0 += NWV * 4 * UT) {
            int a_[UT];
            float w_[UT];
#pragma unroll
            for (int u = 0; u < UT; ++u) {
                int s = min(s0 + u * 4 + sub, hi - 1);
                bool act = (s0 + u * 4 + sub) < hi;
                int i0 = __builtin_nontemporal_load(tris + 3 * s);
                int i1 = __builtin_nontemporal_load(tris + 3 * s + 1);
                int i2 = __builtin_nontemporal_load(tris + 3 * s + 2);
                float w = act ? -__builtin_nontemporal_load(tw + s) : 0.f;
                int A = tabg[(size_t)i0 * GD + dl];
                int B = tabg[(size_t)i1 * GD + dl];
                int C = tabg[(size_t)i2 * GD + dl];
                a_[u] = dl * PADH + max(A, max(B, C));
                w_[u] = w;
            }
#pragma unroll
            for (int u = 0; u < UT; ++u) {
                dedupe4(a_[u], w_[u], lane, pad);
                float v = H[a_[u]];
                H[a_[u]] = v + w_[u];
            }
        }
    }

    __syncthreads();
    flush4(hist, g, out);
}

__global__ void wect_cumsum(float* __restrict__ out) {
    // one wave (64 lanes) per direction row of 256 floats
    int lane = threadIdx.x;
    float4* row = (float4*)out + (size_t)blockIdx.x * 64;
    float4 v = row[lane];
    v.y += v.x;
    v.z += v.y;
    v.w += v.z;
    float s = v.w;
    float mine = s;
    for (int off = 1; off < 64; off <<= 1) {
        float t = __shfl_up(s, off, 64);
        if (lane >= off) s += t;
    }
    float excl = s - mine;
    v.x += excl;
    v.y += excl;
    v.z += excl;
    v.w += excl;
    row[lane] = v;
}

// ---------------- fallback kernels (no workspace) ----------------

__global__ __launch_bounds__(512) void wect_simplex_rec(
    const int* __restrict__ edges, const float* __restrict__ ew,
    const int* __restrict__ tris, const float* __restrict__ tw, int k1, int k2,
    const float* __restrict__ vc, const float* __restrict__ dirs,
    const unsigned* __restrict__ maxbits, float* __restrict__ out) {
    __shared__ float hist[NBINS];
    for (int i = threadIdx.x; i < NBINS; i += blockDim.x) hist[i] = 0.f;
    int lane = threadIdx.x & 63;
    float d0 = dirs[lane * 3], d1 = dirs[lane * 3 + 1], d2 = dirs[lane * 3 + 2];
    float mh = __uint_as_float(*maxbits);
    float inv = 1.0f / (2.0f * mh);
    __syncthreads();
    int wid = (blockIdx.x * blockDim.x + threadIdx.x) >> 6;
    int nw = (gridDim.x * blockDim.x) >> 6;
    int total = k1 + k2;
    for (int s = wid; s < total; s += nw) {
        int idx;
        float w;
        if (s < k1) {
            int v0 = edges[2 * s], v1 = edges[2 * s + 1];
            float h0 = vc[3 * v0] * d0 + vc[3 * v0 + 1] * d1 + vc[3 * v0 + 2] * d2;
            float h1 = vc[3 * v1] * d0 + vc[3 * v1 + 1] * d1 + vc[3 * v1 + 2] * d2;
            idx = max(height_bin(h0, mh, inv), height_bin(h1, mh, inv));
            w = ew[s];
        } else {
            int t = s - k1;
            int v0 = tris[3 * t], v1 = tris[3 * t + 1], v2 = tris[3 * t + 2];
            float h0 = vc[3 * v0] * d0 + vc[3 * v0 + 1] * d1 + vc[3 * v0 + 2] * d2;
            float h1 = vc[3 * v1] * d0 + vc[3 * v1 + 1] * d1 + vc[3 * v1 + 2] * d2;
            float h2 = vc[3 * v2] * d0 + vc[3 * v2 + 1] * d1 + vc[3 * v2 + 2] * d2;
            idx = max(height_bin(h0, mh, inv),
                      max(height_bin(h1, mh, inv), height_bin(h2, mh, inv)));
            w = -tw[t];
        }
        atomicAdd(&hist[idx * NDIR + lane], w);
    }
    __syncthreads();
    for (int i = threadIdx.x; i < NBINS; i += blockDim.x) {
        float v = hist[i];
        if (v != 0.f) atomicAdd(&out[(i & 63) * HGT + (i >> 6)], v);
    }
}

__global__ __launch_bounds__(512) void wect_vertex_rec(
    const float* __restrict__ vc, const float* __restrict__ vw,
    const float* __restrict__ dirs, int k0,
    const unsigned* __restrict__ maxbits, float* __restrict__ out) {
    __shared__ float hist[NBINS];
    for (int i = threadIdx.x; i < NBINS; i += blockDim.x) hist[i] = 0.f;
    int lane = threadIdx.x & 63;
    float d0 = dirs[lane * 3], d1 = dirs[lane * 3 + 1], d2 = dirs[lane * 3 + 2];
    float mh = __uint_as_float(*maxbits);
    float inv = 1.0f / (2.0f * mh);
    __syncthreads();
    int wid = (blockIdx.x * blockDim.x + threadIdx.x) >> 6;
    int nw = (gridDim.x * blockDim.x) >> 6;
    for (int k = wid; k < k0; k += nw) {
        float h = vc[3 * k] * d0 + vc[3 * k + 1] * d1 + vc[3 * k + 2] * d2;
        int idx = height_bin(h, mh, inv);
        atomicAdd(&hist[idx * NDIR + lane], vw[k]);
    }
    __syncthreads();
    for (int i = threadIdx.x; i < NBINS; i += blockDim.x) {
        float v = hist[i];
        if (v != 0.f) atomicAdd(&out[(i & 63) * HGT + (i >> 6)], v);
    }
}

extern "C" void kernel_launch(void* const* d_in, const int* in_sizes, int n_in,
                              void* d_out, int out_size, void* d_ws,
                              size_t ws_size, hipStream_t stream) {
    const float* v_coords = (const float*)d_in[0];
    const float* v_weights = (const float*)d_in[1];
    const int* edges = (const int*)d_in[2];
    const float* e_weights = (const float*)d_in[3];
    const int* tris = (const int*)d_in[4];
    const float* t_weights = (const float*)d_in[5];
    const float* dirs = (const float*)d_in[6];
    // d_in[7] = num_heights (=256, hardcoded as HGT)

    int k0 = in_sizes[0] / 3;
    int k1 = in_sizes[2] / 2;
    int k2 = in_sizes[4] / 3;

    float* out = (float*)d_out;
    unsigned* maxbits = (unsigned*)d_ws;
    unsigned char* tab = (unsigned char*)d_ws + 64;
    bool have_table = ws_size >= 64 + (size_t)NG * k0 * GD;

    (void)hipMemsetAsync(d_ws, 0, 64, stream);
    (void)hipMemsetAsync(d_out, 0, (size_t)NBINS * sizeof(float), stream);

    wect_maxnorm<<<256, 256, 0, stream>>>(v_coords, k0, maxbits);

    if (have_table) {
        wect_vertex4<<<NG * VSL, TPB, 0, stream>>>(v_coords, v_weights, dirs,
                                                   k0, maxbits, tab, out);
        wect_simplex4<<<NG * SSL, TPB, 0, stream>>>(
            (const long long*)edges, e_weights, tris, t_weights, k1, k2, tab,
            k0, out);
    } else {
        wect_vertex_rec<<<512, 512, 0, stream>>>(v_coords, v_weights, dirs, k0,
                                                 maxbits, out);
        wect_simplex_rec<<<512, 512, 0, stream>>>(edges, e_weights, tris,
                                                  t_weights, k1, k2, v_coords,
                                                  dirs, maxbits, out);
    }
    wect_cumsum<<<NDIR, 64, 0, stream>>>(out);
}

// Round 13
// 388.318 us; speedup vs baseline: 1.0256x; 1.0256x over previous
//
#include <hip/hip_runtime.h>

// WECT R12 = R9 (U=2, proven 295us) + occupancy & addressing fixes.
// R11 post-mortem: 7 waves/CU = 1.75/SIMD -> ~200cy/item serial chain fully
// exposed; RMW can't pipeline across u (compiler can't prove no-alias).
// R12: TPB=192 (3 waves x 16.4KB = 49.3KB LDS -> 3 blocks/CU = 9 waves/CU),
// U=2, u32 gather addressing (kill 64-bit mul chains), NT stream loads,
// per-group L2-pinned tables, quad shfl-dedupe with pad redirect.

#define HGT 256
#define NDIR 64
#define NBINS (HGT * NDIR)
#define NG 4
#define GD 16
#define PADH 257
#define WH (GD * PADH)  // 4112 floats per wave
#define TPB 192
#define NWV (TPB / 64)
#define VSL 192
#define SSL 192
#define UE 2
#define UT 2
#define UV 2

__global__ void wect_maxnorm(const float* __restrict__ vc, int k0,
                             unsigned* __restrict__ maxbits) {
    float m = 0.f;
    for (int i = blockIdx.x * blockDim.x + threadIdx.x; i < k0;
         i += gridDim.x * blockDim.x) {
        float x = vc[3 * i], y = vc[3 * i + 1], z = vc[3 * i + 2];
        m = fmaxf(m, sqrtf(x * x + y * y + z * z));
    }
    for (int off = 32; off > 0; off >>= 1)
        m = fmaxf(m, __shfl_down(m, off, 64));
    __shared__ float sm[16];
    int wid = threadIdx.x >> 6, lane = threadIdx.x & 63;
    if (lane == 0) sm[wid] = m;
    __syncthreads();
    if (threadIdx.x == 0) {
        float b = sm[0];
        int nw = blockDim.x >> 6;
        for (int w = 1; w < nw; ++w) b = fmaxf(b, sm[w]);
        atomicMax(maxbits, __float_as_uint(b));  // valid: all values >= 0
    }
}

__device__ __forceinline__ int height_bin(float h, float mh, float inv) {
    int idx = (int)ceilf((255.0f * (mh + h)) * inv);
    return min(max(idx, 0), HGT - 1);
}

// Merge same-address lanes within the xor-quad {l, l^16, l^32, l^48}.
// All 6 pairs covered by masks 16,32,48. Upper lane of a matching pair
// donates w and retargets the (harmless, unread) pad column.
__device__ __forceinline__ void dedupe4(int& a, float& w, int lane, int pad) {
#pragma unroll
    for (int m = 16; m <= 48; m += 16) {
        int pa = __shfl_xor(a, m, 64);
        float pw = __shfl_xor(w, m, 64);
        bool match = (pa == a);
        bool upper = lane > (lane ^ m);
        if (match) {
            if (upper) {
                w = 0.f;
                a = pad;
            } else {
                w += pw;
            }
        }
    }
}

__device__ __forceinline__ void flush4(const float* hist, int g,
                                       float* __restrict__ out) {
    for (int t = threadIdx.x; t < GD * HGT; t += TPB) {
        int d = t >> 8, b = t & 255;
        float s = 0.f;
#pragma unroll
        for (int u = 0; u < NWV; ++u) s += hist[u * WH + d * PADH + b];
        if (s != 0.f) atomicAdd(&out[(g * GD + d) * HGT + b], s);
    }
}

__global__ __launch_bounds__(TPB) void wect_vertex4(
    const float* __restrict__ vc, const float* __restrict__ vw,
    const float* __restrict__ dirs, int k0,
    const unsigned* __restrict__ maxbits, unsigned char* __restrict__ tab,
    float* __restrict__ out) {
    __shared__ float hist[NWV * WH];
    int tid = threadIdx.x, lane = tid & 63, wv = tid >> 6;
    int dl = lane & 15, sub = lane >> 4;
    for (int t = tid; t < NWV * WH; t += TPB) hist[t] = 0.f;
    int g = blockIdx.x & (NG - 1);
    int slice = blockIdx.x >> 2;
    int gd = g * GD + dl;
    float dx = dirs[3 * gd], dy = dirs[3 * gd + 1], dz = dirs[3 * gd + 2];
    float mh = __uint_as_float(*maxbits);
    float inv = 1.0f / (2.0f * mh);
    unsigned char* tabg = tab + (size_t)g * ((size_t)k0 * GD);
    float* H = hist + wv * WH;
    int pad = dl * PADH + 256;
    __syncthreads();
    int lo = (int)((long long)k0 * slice / VSL);
    int hi = (int)((long long)k0 * (slice + 1) / VSL);
    for (int s0 = lo + wv * 4 * UV; s0 < hi; s0 += NWV * 4 * UV) {
        int a_[UV];
        float w_[UV];
#pragma unroll
        for (int u = 0; u < UV; ++u) {
            int s = min(s0 + u * 4 + sub, hi - 1);
            bool act = (s0 + u * 4 + sub) < hi;
            float x = vc[3 * s], y = vc[3 * s + 1], z = vc[3 * s + 2];
            float w = act ? vw[s] : 0.f;
            float h = fmaf(x, dx, fmaf(y, dy, z * dz));
            int b = height_bin(h, mh, inv);
            if (act) tabg[(unsigned)s * GD + dl] = (unsigned char)b;
            a_[u] = dl * PADH + b;
            w_[u] = w;
        }
#pragma unroll
        for (int u = 0; u < UV; ++u) {
            dedupe4(a_[u], w_[u], lane, pad);
            float v = H[a_[u]];
            H[a_[u]] = v + w_[u];
        }
    }
    __syncthreads();
    flush4(hist, g, out);
}

__global__ __launch_bounds__(TPB) void wect_simplex4(
    const long long* __restrict__ edges, const float* __restrict__ ew,
    const int* __restrict__ tris, const float* __restrict__ tw, int k1, int k2,
    const unsigned char* __restrict__ tab, int k0, float* __restrict__ out) {
    __shared__ float hist[NWV * WH];
    int tid = threadIdx.x, lane = tid & 63, wv = tid >> 6;
    int dl = lane & 15, sub = lane >> 4;
    for (int t = tid; t < NWV * WH; t += TPB) hist[t] = 0.f;
    int g = blockIdx.x & (NG - 1);
    int slice = blockIdx.x >> 2;
    const unsigned char* tabg = tab + (size_t)g * ((size_t)k0 * GD);
    float* H = hist + wv * WH;
    int pad = dl * PADH + 256;
    __syncthreads();

    // ---- edges: +w, max over 2 endpoints ----
    {
        int lo = (int)((long long)k1 * slice / SSL);
        int hi = (int)((long long)k1 * (slice + 1) / SSL);
        for (int s0 = lo + wv * 4 * UE; s0 < hi; s0 += NWV * 4 * UE) {
            int a_[UE];
            float w_[UE];
#pragma unroll
            for (int u = 0; u < UE; ++u) {
                int s = min(s0 + u * 4 + sub, hi - 1);
                bool act = (s0 + u * 4 + sub) < hi;
                long long ep = __builtin_nontemporal_load(edges + s);
                float w = act ? __builtin_nontemporal_load(ew + s) : 0.f;
                unsigned ex = (unsigned)(ep & 0xffffffffLL);
                unsigned ey = (unsigned)(ep >> 32);
                int A = tabg[ex * GD + dl];
                int B = tabg[ey * GD + dl];
                a_[u] = dl * PADH + max(A, B);
                w_[u] = w;
            }
#pragma unroll
            for (int u = 0; u < UE; ++u) {
                dedupe4(a_[u], w_[u], lane, pad);
                float v = H[a_[u]];
                H[a_[u]] = v + w_[u];
            }
        }
    }

    // ---- triangles: -w, max over 3 endpoints ----
    {
        int lo = (int)((long long)k2 * slice / SSL);
        int hi = (int)((long long)k2 * (slice + 1) / SSL);
        for (int s0 = lo + wv * 4 * UT; s0 < hi; s0 += NWV * 4 * UT) {
            int a_[UT];
            float w_[UT];
#pragma unroll
            for (int u = 0; u < UT; ++u) {
                int s = min(s0 + u * 4 + sub, hi - 1);
                bool act = (s0 + u * 4 + sub) < hi;
                unsigned i0 = (unsigned)__builtin_nontemporal_load(tris + 3 * s);
                unsigned i1 =
                    (unsigned)__builtin_nontemporal_load(tris + 3 * s + 1);
                unsigned i2 =
                    (unsigned)__builtin_nontemporal_load(tris + 3 * s + 2);
                float w = act ? -__builtin_nontemporal_load(tw + s) : 0.f;
                int A = tabg[i0 * GD + dl];
                int B = tabg[i1 * GD + dl];
                int C = tabg[i2 * GD + dl];
                a_[u] = dl * PADH + max(A, max(B, C));
                w_[u] = w;
            }
#pragma unroll
            for (int u = 0; u < UT; ++u) {
                dedupe4(a_[u], w_[u], lane, pad);
                float v = H[a_[u]];
                H[a_[u]] = v + w_[u];
            }
        }
    }

    __syncthreads();
    flush4(hist, g, out);
}

__global__ void wect_cumsum(float* __restrict__ out) {
    // one wave (64 lanes) per direction row of 256 floats
    int lane = threadIdx.x;
    float4* row = (float4*)out + (size_t)blockIdx.x * 64;
    float4 v = row[lane];
    v.y += v.x;
    v.z += v.y;
    v.w += v.z;
    float s = v.w;
    float mine = s;
    for (int off = 1; off < 64; off <<= 1) {
        float t = __shfl_up(s, off, 64);
        if (lane >= off) s += t;
    }
    float excl = s - mine;
    v.x += excl;
    v.y += excl;
    v.z += excl;
    v.w += excl;
    row[lane] = v;
}

// ---------------- fallback kernels (no workspace) ----------------

__global__ __launch_bounds__(512) void wect_simplex_rec(
    const int* __restrict__ edges, const float* __restrict__ ew,
    const int* __restrict__ tris, const float* __restrict__ tw, int k1, int k2,
    const float* __restrict__ vc, const float* __restrict__ dirs,
    const unsigned* __restrict__ maxbits, float* __restrict__ out) {
    __shared__ float hist[NBINS];
    for (int i = threadIdx.x; i < NBINS; i += blockDim.x) hist[i] = 0.f;
    int lane = threadIdx.x & 63;
    float d0 = dirs[lane * 3], d1 = dirs[lane * 3 + 1], d2 = dirs[lane * 3 + 2];
    float mh = __uint_as_float(*maxbits);
    float inv = 1.0f / (2.0f * mh);
    __syncthreads();
    int wid = (blockIdx.x * blockDim.x + threadIdx.x) >> 6;
    int nw = (gridDim.x * blockDim.x) >> 6;
    int total = k1 + k2;
    for (int s = wid; s < total; s += nw) {
        int idx;
        float w;
        if (s < k1) {
            int v0 = edges[2 * s], v1 = edges[2 * s + 1];
            float h0 = vc[3 * v0] * d0 + vc[3 * v0 + 1] * d1 + vc[3 * v0 + 2] * d2;
            float h1 = vc[3 * v1] * d0 + vc[3 * v1 + 1] * d1 + vc[3 * v1 + 2] * d2;
            idx = max(height_bin(h0, mh, inv), height_bin(h1, mh, inv));
            w = ew[s];
        } else {
            int t = s - k1;
            int v0 = tris[3 * t], v1 = tris[3 * t + 1], v2 = tris[3 * t + 2];
            float h0 = vc[3 * v0] * d0 + vc[3 * v0 + 1] * d1 + vc[3 * v0 + 2] * d2;
            float h1 = vc[3 * v1] * d0 + vc[3 * v1 + 1] * d1 + vc[3 * v1 + 2] * d2;
            float h2 = vc[3 * v2] * d0 + vc[3 * v2 + 1] * d1 + vc[3 * v2 + 2] * d2;
            idx = max(height_bin(h0, mh, inv),
                      max(height_bin(h1, mh, inv), height_bin(h2, mh, inv)));
            w = -tw[t];
        }
        atomicAdd(&hist[idx * NDIR + lane], w);
    }
    __syncthreads();
    for (int i = threadIdx.x; i < NBINS; i += blockDim.x) {
        float v = hist[i];
        if (v != 0.f) atomicAdd(&out[(i & 63) * HGT + (i >> 6)], v);
    }
}

__global__ __launch_bounds__(512) void wect_vertex_rec(
    const float* __restrict__ vc, const float* __restrict__ vw,
    const float* __restrict__ dirs, int k0,
    const unsigned* __restrict__ maxbits, float* __restrict__ out) {
    __shared__ float hist[NBINS];
    for (int i = threadIdx.x; i < NBINS; i += blockDim.x) hist[i] = 0.f;
    int lane = threadIdx.x & 63;
    float d0 = dirs[lane * 3], d1 = dirs[lane * 3 + 1], d2 = dirs[lane * 3 + 2];
    float mh = __uint_as_float(*maxbits);
    float inv = 1.0f / (2.0f * mh);
    __syncthreads();
    int wid = (blockIdx.x * blockDim.x + threadIdx.x) >> 6;
    int nw = (gridDim.x * blockDim.x) >> 6;
    for (int k = wid; k < k0; k += nw) {
        float h = vc[3 * k] * d0 + vc[3 * k + 1] * d1 + vc[3 * k + 2] * d2;
        int idx = height_bin(h, mh, inv);
        atomicAdd(&hist[idx * NDIR + lane], vw[k]);
    }
    __syncthreads();
    for (int i = threadIdx.x; i < NBINS; i += blockDim.x) {
        float v = hist[i];
        if (v != 0.f) atomicAdd(&out[(i & 63) * HGT + (i >> 6)], v);
    }
}

extern "C" void kernel_launch(void* const* d_in, const int* in_sizes, int n_in,
                              void* d_out, int out_size, void* d_ws,
                              size_t ws_size, hipStream_t stream) {
    const float* v_coords = (const float*)d_in[0];
    const float* v_weights = (const float*)d_in[1];
    const int* edges = (const int*)d_in[2];
    const float* e_weights = (const float*)d_in[3];
    const int* tris = (const int*)d_in[4];
    const float* t_weights = (const float*)d_in[5];
    const float* dirs = (const float*)d_in[6];
    // d_in[7] = num_heights (=256, hardcoded as HGT)

    int k0 = in_sizes[0] / 3;
    int k1 = in_sizes[2] / 2;
    int k2 = in_sizes[4] / 3;

    float* out = (float*)d_out;
    unsigned* maxbits = (unsigned*)d_ws;
    unsigned char* tab = (unsigned char*)d_ws + 64;
    bool have_table = ws_size >= 64 + (size_t)NG * k0 * GD;

    (void)hipMemsetAsync(d_ws, 0, 64, stream);
    (void)hipMemsetAsync(d_out, 0, (size_t)NBINS * sizeof(float), stream);

    wect_maxnorm<<<256, 256, 0, stream>>>(v_coords, k0, maxbits);

    if (have_table) {
        wect_vertex4<<<NG * VSL, TPB, 0, stream>>>(v_coords, v_weights, dirs,
                                                   k0, maxbits, tab, out);
        wect_simplex4<<<NG * SSL, TPB, 0, stream>>>(
            (const long long*)edges, e_weights, tris, t_weights, k1, k2, tab,
            k0, out);
    } else {
        wect_vertex_rec<<<512, 512, 0, stream>>>(v_coords, v_weights, dirs, k0,
                                                 maxbits, out);
        wect_simplex_rec<<<512, 512, 0, stream>>>(edges, e_weights, tris,
                                                  t_weights, k1, k2, v_coords,
                                                  dirs, maxbits, out);
    }
    wect_cumsum<<<NDIR, 64, 0, stream>>>(out);
}

// Round 14
// 270.236 us; speedup vs baseline: 1.4737x; 1.4370x over previous
//
#include <hip/hip_runtime.h>

// WECT R13 = R12 + fp16 wave-private histograms -> 2x occupancy.
// R12 analysis: f32 hist 16.4KB/wave caps at 9 waves/CU (LDS 160KB); chain
// ~3500cy/iter exposed at 2.25 waves/SIMD. fp16 hist = 8.3KB/wave ->
// TPB=256 x 4 waves (33KB) x 4 blocks/CU = 16 waves/CU (4/SIMD).
// Bin swizzle p=((b&1)<<7)|(b>>1) keeps adjacent bins in different dwords
// (no same-dword u16 write hazards). Flush converts fp16->f32, un-swizzles.
// Rest identical to R12: GD=16, quad shfl-dedupe, U=2, per-u serial RMW,
// NT stream loads, per-group L2-pinned u8 tables (3.2MB/XCD).

#define HGT 256
#define NDIR 64
#define NBINS (HGT * NDIR)
#define NG 4
#define GD 16
#define PADH16 258
#define WH16 (GD * PADH16)  // 4128 fp16 per wave
#define TPB 256
#define NWV (TPB / 64)
#define VSL 256
#define SSL 256
#define UE 2
#define UT 2
#define UV 2

__global__ void wect_maxnorm(const float* __restrict__ vc, int k0,
                             unsigned* __restrict__ maxbits) {
    float m = 0.f;
    for (int i = blockIdx.x * blockDim.x + threadIdx.x; i < k0;
         i += gridDim.x * blockDim.x) {
        float x = vc[3 * i], y = vc[3 * i + 1], z = vc[3 * i + 2];
        m = fmaxf(m, sqrtf(x * x + y * y + z * z));
    }
    for (int off = 32; off > 0; off >>= 1)
        m = fmaxf(m, __shfl_down(m, off, 64));
    __shared__ float sm[16];
    int wid = threadIdx.x >> 6, lane = threadIdx.x & 63;
    if (lane == 0) sm[wid] = m;
    __syncthreads();
    if (threadIdx.x == 0) {
        float b = sm[0];
        int nw = blockDim.x >> 6;
        for (int w = 1; w < nw; ++w) b = fmaxf(b, sm[w]);
        atomicMax(maxbits, __float_as_uint(b));  // valid: all values >= 0
    }
}

__device__ __forceinline__ int height_bin(float h, float mh, float inv) {
    int idx = (int)ceilf((255.0f * (mh + h)) * inv);
    return min(max(idx, 0), HGT - 1);
}

// u16-element offset inside a wave hist for (dir dl, bin b):
// swizzled so bins b and b+1 are 256B apart (different dwords/banks).
__device__ __forceinline__ int haddr(int dl, int b) {
    int p = ((b & 1) << 7) | (b >> 1);
    return dl * PADH16 + p;
}

// Merge same-address lanes within the xor-quad {l, l^16, l^32, l^48}.
// All 6 pairs covered by masks 16,32,48. Upper lane of a matching pair
// donates w and retargets the (harmless, unread) pad slot.
__device__ __forceinline__ void dedupe4(int& a, float& w, int lane, int pad) {
#pragma unroll
    for (int m = 16; m <= 48; m += 16) {
        int pa = __shfl_xor(a, m, 64);
        float pw = __shfl_xor(w, m, 64);
        bool match = (pa == a);
        bool upper = lane > (lane ^ m);
        if (match) {
            if (upper) {
                w = 0.f;
                a = pad;
            } else {
                w += pw;
            }
        }
    }
}

__device__ __forceinline__ void flush5(const _Float16* hist, int g,
                                       float* __restrict__ out) {
    for (int t = threadIdx.x; t < GD * HGT; t += TPB) {
        int d = t >> 8, b = t & 255;
        int p = d * PADH16 + (((b & 1) << 7) | (b >> 1));
        float s = 0.f;
#pragma unroll
        for (int u = 0; u < NWV; ++u) s += (float)hist[u * WH16 + p];
        if (s != 0.f) atomicAdd(&out[(g * GD + d) * HGT + b], s);
    }
}

__global__ __launch_bounds__(TPB, 4) void wect_vertex4(
    const float* __restrict__ vc, const float* __restrict__ vw,
    const float* __restrict__ dirs, int k0,
    const unsigned* __restrict__ maxbits, unsigned char* __restrict__ tab,
    float* __restrict__ out) {
    __shared__ _Float16 hist[NWV * WH16];
    int tid = threadIdx.x, lane = tid & 63, wv = tid >> 6;
    int dl = lane & 15, sub = lane >> 4;
    for (int t = tid; t < NWV * WH16; t += TPB) hist[t] = (_Float16)0.f;
    int g = blockIdx.x & (NG - 1);
    int slice = blockIdx.x >> 2;
    int gd = g * GD + dl;
    float dx = dirs[3 * gd], dy = dirs[3 * gd + 1], dz = dirs[3 * gd + 2];
    float mh = __uint_as_float(*maxbits);
    float inv = 1.0f / (2.0f * mh);
    unsigned char* tabg = tab + (size_t)g * ((size_t)k0 * GD);
    _Float16* H = hist + wv * WH16;
    int pad = dl * PADH16 + 256;
    __syncthreads();
    int lo = (int)((long long)k0 * slice / VSL);
    int hi = (int)((long long)k0 * (slice + 1) / VSL);
    for (int s0 = lo + wv * 4 * UV; s0 < hi; s0 += NWV * 4 * UV) {
        int a_[UV];
        float w_[UV];
#pragma unroll
        for (int u = 0; u < UV; ++u) {
            int s = min(s0 + u * 4 + sub, hi - 1);
            bool act = (s0 + u * 4 + sub) < hi;
            float x = vc[3 * s], y = vc[3 * s + 1], z = vc[3 * s + 2];
            float w = act ? vw[s] : 0.f;
            float h = fmaf(x, dx, fmaf(y, dy, z * dz));
            int b = height_bin(h, mh, inv);
            if (act) tabg[(unsigned)s * GD + dl] = (unsigned char)b;
            a_[u] = haddr(dl, b);
            w_[u] = w;
        }
#pragma unroll
        for (int u = 0; u < UV; ++u) {
            dedupe4(a_[u], w_[u], lane, pad);
            _Float16 v = H[a_[u]];
            H[a_[u]] = v + (_Float16)w_[u];
        }
    }
    __syncthreads();
    flush5(hist, g, out);
}

__global__ __launch_bounds__(TPB, 4) void wect_simplex4(
    const long long* __restrict__ edges, const float* __restrict__ ew,
    const int* __restrict__ tris, const float* __restrict__ tw, int k1, int k2,
    const unsigned char* __restrict__ tab, int k0, float* __restrict__ out) {
    __shared__ _Float16 hist[NWV * WH16];
    int tid = threadIdx.x, lane = tid & 63, wv = tid >> 6;
    int dl = lane & 15, sub = lane >> 4;
    for (int t = tid; t < NWV * WH16; t += TPB) hist[t] = (_Float16)0.f;
    int g = blockIdx.x & (NG - 1);
    int slice = blockIdx.x >> 2;
    const unsigned char* tabg = tab + (size_t)g * ((size_t)k0 * GD);
    _Float16* H = hist + wv * WH16;
    int pad = dl * PADH16 + 256;
    __syncthreads();

    // ---- edges: +w, max over 2 endpoints ----
    {
        int lo = (int)((long long)k1 * slice / SSL);
        int hi = (int)((long long)k1 * (slice + 1) / SSL);
        for (int s0 = lo + wv * 4 * UE; s0 < hi; s0 += NWV * 4 * UE) {
            int a_[UE];
            float w_[UE];
#pragma unroll
            for (int u = 0; u < UE; ++u) {
                int s = min(s0 + u * 4 + sub, hi - 1);
                bool act = (s0 + u * 4 + sub) < hi;
                long long ep = __builtin_nontemporal_load(edges + s);
                float w = act ? __builtin_nontemporal_load(ew + s) : 0.f;
                unsigned ex = (unsigned)(ep & 0xffffffffLL);
                unsigned ey = (unsigned)(ep >> 32);
                int A = tabg[ex * GD + dl];
                int B = tabg[ey * GD + dl];
                a_[u] = haddr(dl, max(A, B));
                w_[u] = w;
            }
#pragma unroll
            for (int u = 0; u < UE; ++u) {
                dedupe4(a_[u], w_[u], lane, pad);
                _Float16 v = H[a_[u]];
                H[a_[u]] = v + (_Float16)w_[u];
            }
        }
    }

    // ---- triangles: -w, max over 3 endpoints ----
    {
        int lo = (int)((long long)k2 * slice / SSL);
        int hi = (int)((long long)k2 * (slice + 1) / SSL);
        for (int s0 = lo + wv * 4 * UT; s0 < hi; s0 += NWV * 4 * UT) {
            int a_[UT];
            float w_[UT];
#pragma unroll
            for (int u = 0; u < UT; ++u) {
                int s = min(s0 + u * 4 + sub, hi - 1);
                bool act = (s0 + u * 4 + sub) < hi;
                unsigned i0 = (unsigned)__builtin_nontemporal_load(tris + 3 * s);
                unsigned i1 =
                    (unsigned)__builtin_nontemporal_load(tris + 3 * s + 1);
                unsigned i2 =
                    (unsigned)__builtin_nontemporal_load(tris + 3 * s + 2);
                float w = act ? -__builtin_nontemporal_load(tw + s) : 0.f;
                int A = tabg[i0 * GD + dl];
                int B = tabg[i1 * GD + dl];
                int C = tabg[i2 * GD + dl];
                a_[u] = haddr(dl, max(A, max(B, C)));
                w_[u] = w;
            }
#pragma unroll
            for (int u = 0; u < UT; ++u) {
                dedupe4(a_[u], w_[u], lane, pad);
                _Float16 v = H[a_[u]];
                H[a_[u]] = v + (_Float16)w_[u];
            }
        }
    }

    __syncthreads();
    flush5(hist, g, out);
}

__global__ void wect_cumsum(float* __restrict__ out) {
    // one wave (64 lanes) per direction row of 256 floats
    int lane = threadIdx.x;
    float4* row = (float4*)out + (size_t)blockIdx.x * 64;
    float4 v = row[lane];
    v.y += v.x;
    v.z += v.y;
    v.w += v.z;
    float s = v.w;
    float mine = s;
    for (int off = 1; off < 64; off <<= 1) {
        float t = __shfl_up(s, off, 64);
        if (lane >= off) s += t;
    }
    float excl = s - mine;
    v.x += excl;
    v.y += excl;
    v.z += excl;
    v.w += excl;
    row[lane] = v;
}

// ---------------- fallback kernels (no workspace) ----------------

__global__ __launch_bounds__(512) void wect_simplex_rec(
    const int* __restrict__ edges, const float* __restrict__ ew,
    const int* __restrict__ tris, const float* __restrict__ tw, int k1, int k2,
    const float* __restrict__ vc, const float* __restrict__ dirs,
    const unsigned* __restrict__ maxbits, float* __restrict__ out) {
    __shared__ float hist[NBINS];
    for (int i = threadIdx.x; i < NBINS; i += blockDim.x) hist[i] = 0.f;
    int lane = threadIdx.x & 63;
    float d0 = dirs[lane * 3], d1 = dirs[lane * 3 + 1], d2 = dirs[lane * 3 + 2];
    float mh = __uint_as_float(*maxbits);
    float inv = 1.0f / (2.0f * mh);
    __syncthreads();
    int wid = (blockIdx.x * blockDim.x + threadIdx.x) >> 6;
    int nw = (gridDim.x * blockDim.x) >> 6;
    int total = k1 + k2;
    for (int s = wid; s < total; s += nw) {
        int idx;
        float w;
        if (s < k1) {
            int v0 = edges[2 * s], v1 = edges[2 * s + 1];
            float h0 = vc[3 * v0] * d0 + vc[3 * v0 + 1] * d1 + vc[3 * v0 + 2] * d2;
            float h1 = vc[3 * v1] * d0 + vc[3 * v1 + 1] * d1 + vc[3 * v1 + 2] * d2;
            idx = max(height_bin(h0, mh, inv), height_bin(h1, mh, inv));
            w = ew[s];
        } else {
            int t = s - k1;
            int v0 = tris[3 * t], v1 = tris[3 * t + 1], v2 = tris[3 * t + 2];
            float h0 = vc[3 * v0] * d0 + vc[3 * v0 + 1] * d1 + vc[3 * v0 + 2] * d2;
            float h1 = vc[3 * v1] * d0 + vc[3 * v1 + 1] * d1 + vc[3 * v1 + 2] * d2;
            float h2 = vc[3 * v2] * d0 + vc[3 * v2 + 1] * d1 + vc[3 * v2 + 2] * d2;
            idx = max(height_bin(h0, mh, inv),
                      max(height_bin(h1, mh, inv), height_bin(h2, mh, inv)));
            w = -tw[t];
        }
        atomicAdd(&hist[idx * NDIR + lane], w);
    }
    __syncthreads();
    for (int i = threadIdx.x; i < NBINS; i += blockDim.x) {
        float v = hist[i];
        if (v != 0.f) atomicAdd(&out[(i & 63) * HGT + (i >> 6)], v);
    }
}

__global__ __launch_bounds__(512) void wect_vertex_rec(
    const float* __restrict__ vc, const float* __restrict__ vw,
    const float* __restrict__ dirs, int k0,
    const unsigned* __restrict__ maxbits, float* __restrict__ out) {
    __shared__ float hist[NBINS];
    for (int i = threadIdx.x; i < NBINS; i += blockDim.x) hist[i] = 0.f;
    int lane = threadIdx.x & 63;
    float d0 = dirs[lane * 3], d1 = dirs[lane * 3 + 1], d2 = dirs[lane * 3 + 2];
    float mh = __uint_as_float(*maxbits);
    float inv = 1.0f / (2.0f * mh);
    __syncthreads();
    int wid = (blockIdx.x * blockDim.x + threadIdx.x) >> 6;
    int nw = (gridDim.x * blockDim.x) >> 6;
    for (int k = wid; k < k0; k += nw) {
        float h = vc[3 * k] * d0 + vc[3 * k + 1] * d1 + vc[3 * k + 2] * d2;
        int idx = height_bin(h, mh, inv);
        atomicAdd(&hist[idx * NDIR + lane], vw[k]);
    }
    __syncthreads();
    for (int i = threadIdx.x; i < NBINS; i += blockDim.x) {
        float v = hist[i];
        if (v != 0.f) atomicAdd(&out[(i & 63) * HGT + (i >> 6)], v);
    }
}

extern "C" void kernel_launch(void* const* d_in, const int* in_sizes, int n_in,
                              void* d_out, int out_size, void* d_ws,
                              size_t ws_size, hipStream_t stream) {
    const float* v_coords = (const float*)d_in[0];
    const float* v_weights = (const float*)d_in[1];
    const int* edges = (const int*)d_in[2];
    const float* e_weights = (const float*)d_in[3];
    const int* tris = (const int*)d_in[4];
    const float* t_weights = (const float*)d_in[5];
    const float* dirs = (const float*)d_in[6];
    // d_in[7] = num_heights (=256, hardcoded as HGT)

    int k0 = in_sizes[0] / 3;
    int k1 = in_sizes[2] / 2;
    int k2 = in_sizes[4] / 3;

    float* out = (float*)d_out;
    unsigned* maxbits = (unsigned*)d_ws;
    unsigned char* tab = (unsigned char*)d_ws + 64;
    bool have_table = ws_size >= 64 + (size_t)NG * k0 * GD;

    (void)hipMemsetAsync(d_ws, 0, 64, stream);
    (void)hipMemsetAsync(d_out, 0, (size_t)NBINS * sizeof(float), stream);

    wect_maxnorm<<<256, 256, 0, stream>>>(v_coords, k0, maxbits);

    if (have_table) {
        wect_vertex4<<<NG * VSL, TPB, 0, stream>>>(v_coords, v_weights, dirs,
                                                   k0, maxbits, tab, out);
        wect_simplex4<<<NG * SSL, TPB, 0, stream>>>(
            (const long long*)edges, e_weights, tris, t_weights, k1, k2, tab,
            k0, out);
    } else {
        wect_vertex_rec<<<512, 512, 0, stream>>>(v_coords, v_weights, dirs, k0,
                                                 maxbits, out);
        wect_simplex_rec<<<512, 512, 0, stream>>>(edges, e_weights, tris,
                                                  t_weights, k1, k2, v_coords,
                                                  dirs, maxbits, out);
    }
    wect_cumsum<<<NDIR, 64, 0, stream>>>(out);
}

// Round 15
// 223.959 us; speedup vs baseline: 1.7782x; 1.2066x over previous
//
#include <hip/hip_runtime.h>

// WECT R14 = R13 minus nontemporal loads, plus 18 waves/CU.
// R13 post-mortem: chain = 2100cy/item vs 1350 in R9 -> the NT stream loads
// (added R10) bypass L2/L3 and put ~900cy HBM latency INTO the dependent
// chain (gather addr depends on edge load). Streams are re-read 4x and must
// cache. Also TPB 256->192: 3 waves x 8.3KB fp16 hist = 24.8KB/block ->
// 6 blocks/CU = 18 waves/CU (was 14).
// Structure (proven R9/R13): GD=16 dirs/group, wave-private fp16 hist,
// quad shfl-dedupe {16,32,48} with pad redirect, U=2, per-u serial RMW,
// per-group L2-pinned u8 tables, bin swizzle for u16 dword separation.

#define HGT 256
#define NDIR 64
#define NBINS (HGT * NDIR)
#define NG 4
#define GD 16
#define PADH16 258
#define WH16 (GD * PADH16)  // 4128 fp16 per wave
#define TPB 192
#define NWV (TPB / 64)
#define VSL 384
#define SSL 384
#define UE 2
#define UT 2
#define UV 2

__global__ void wect_maxnorm(const float* __restrict__ vc, int k0,
                             unsigned* __restrict__ maxbits) {
    float m = 0.f;
    for (int i = blockIdx.x * blockDim.x + threadIdx.x; i < k0;
         i += gridDim.x * blockDim.x) {
        float x = vc[3 * i], y = vc[3 * i + 1], z = vc[3 * i + 2];
        m = fmaxf(m, sqrtf(x * x + y * y + z * z));
    }
    for (int off = 32; off > 0; off >>= 1)
        m = fmaxf(m, __shfl_down(m, off, 64));
    __shared__ float sm[16];
    int wid = threadIdx.x >> 6, lane = threadIdx.x & 63;
    if (lane == 0) sm[wid] = m;
    __syncthreads();
    if (threadIdx.x == 0) {
        float b = sm[0];
        int nw = blockDim.x >> 6;
        for (int w = 1; w < nw; ++w) b = fmaxf(b, sm[w]);
        atomicMax(maxbits, __float_as_uint(b));  // valid: all values >= 0
    }
}

__device__ __forceinline__ int height_bin(float h, float mh, float inv) {
    int idx = (int)ceilf((255.0f * (mh + h)) * inv);
    return min(max(idx, 0), HGT - 1);
}

// u16-element offset inside a wave hist for (dir dl, bin b):
// swizzled so bins b and b+1 are 256B apart (different dwords/banks).
__device__ __forceinline__ int haddr(int dl, int b) {
    int p = ((b & 1) << 7) | (b >> 1);
    return dl * PADH16 + p;
}

// Merge same-address lanes within the xor-quad {l, l^16, l^32, l^48}.
// All 6 pairs covered by masks 16,32,48. Upper lane of a matching pair
// donates w and retargets the (harmless, unread) pad slot.
__device__ __forceinline__ void dedupe4(int& a, float& w, int lane, int pad) {
#pragma unroll
    for (int m = 16; m <= 48; m += 16) {
        int pa = __shfl_xor(a, m, 64);
        float pw = __shfl_xor(w, m, 64);
        bool match = (pa == a);
        bool upper = lane > (lane ^ m);
        if (match) {
            if (upper) {
                w = 0.f;
                a = pad;
            } else {
                w += pw;
            }
        }
    }
}

__device__ __forceinline__ void flush5(const _Float16* hist, int g,
                                       float* __restrict__ out) {
    for (int t = threadIdx.x; t < GD * HGT; t += TPB) {
        int d = t >> 8, b = t & 255;
        int p = d * PADH16 + (((b & 1) << 7) | (b >> 1));
        float s = 0.f;
#pragma unroll
        for (int u = 0; u < NWV; ++u) s += (float)hist[u * WH16 + p];
        if (s != 0.f) atomicAdd(&out[(g * GD + d) * HGT + b], s);
    }
}

__global__ __launch_bounds__(TPB, 4) void wect_vertex4(
    const float* __restrict__ vc, const float* __restrict__ vw,
    const float* __restrict__ dirs, int k0,
    const unsigned* __restrict__ maxbits, unsigned char* __restrict__ tab,
    float* __restrict__ out) {
    __shared__ _Float16 hist[NWV * WH16];
    int tid = threadIdx.x, lane = tid & 63, wv = tid >> 6;
    int dl = lane & 15, sub = lane >> 4;
    for (int t = tid; t < NWV * WH16; t += TPB) hist[t] = (_Float16)0.f;
    int g = blockIdx.x & (NG - 1);
    int slice = blockIdx.x >> 2;
    int gd = g * GD + dl;
    float dx = dirs[3 * gd], dy = dirs[3 * gd + 1], dz = dirs[3 * gd + 2];
    float mh = __uint_as_float(*maxbits);
    float inv = 1.0f / (2.0f * mh);
    unsigned char* tabg = tab + (size_t)g * ((size_t)k0 * GD);
    _Float16* H = hist + wv * WH16;
    int pad = dl * PADH16 + 256;
    __syncthreads();
    int lo = (int)((long long)k0 * slice / VSL);
    int hi = (int)((long long)k0 * (slice + 1) / VSL);
    for (int s0 = lo + wv * 4 * UV; s0 < hi; s0 += NWV * 4 * UV) {
        int a_[UV];
        float w_[UV];
#pragma unroll
        for (int u = 0; u < UV; ++u) {
            int s = min(s0 + u * 4 + sub, hi - 1);
            bool act = (s0 + u * 4 + sub) < hi;
            float x = vc[3 * s], y = vc[3 * s + 1], z = vc[3 * s + 2];
            float w = act ? vw[s] : 0.f;
            float h = fmaf(x, dx, fmaf(y, dy, z * dz));
            int b = height_bin(h, mh, inv);
            if (act) tabg[(unsigned)s * GD + dl] = (unsigned char)b;
            a_[u] = haddr(dl, b);
            w_[u] = w;
        }
#pragma unroll
        for (int u = 0; u < UV; ++u) {
            dedupe4(a_[u], w_[u], lane, pad);
            _Float16 v = H[a_[u]];
            H[a_[u]] = v + (_Float16)w_[u];
        }
    }
    __syncthreads();
    flush5(hist, g, out);
}

__global__ __launch_bounds__(TPB, 4) void wect_simplex4(
    const long long* __restrict__ edges, const float* __restrict__ ew,
    const int* __restrict__ tris, const float* __restrict__ tw, int k1, int k2,
    const unsigned char* __restrict__ tab, int k0, float* __restrict__ out) {
    __shared__ _Float16 hist[NWV * WH16];
    int tid = threadIdx.x, lane = tid & 63, wv = tid >> 6;
    int dl = lane & 15, sub = lane >> 4;
    for (int t = tid; t < NWV * WH16; t += TPB) hist[t] = (_Float16)0.f;
    int g = blockIdx.x & (NG - 1);
    int slice = blockIdx.x >> 2;
    const unsigned char* tabg = tab + (size_t)g * ((size_t)k0 * GD);
    _Float16* H = hist + wv * WH16;
    int pad = dl * PADH16 + 256;
    __syncthreads();

    // ---- edges: +w, max over 2 endpoints ----
    {
        int lo = (int)((long long)k1 * slice / SSL);
        int hi = (int)((long long)k1 * (slice + 1) / SSL);
        for (int s0 = lo + wv * 4 * UE; s0 < hi; s0 += NWV * 4 * UE) {
            int a_[UE];
            float w_[UE];
#pragma unroll
            for (int u = 0; u < UE; ++u) {
                int s = min(s0 + u * 4 + sub, hi - 1);
                bool act = (s0 + u * 4 + sub) < hi;
                long long ep = edges[s];
                float w = act ? ew[s] : 0.f;
                unsigned ex = (unsigned)(ep & 0xffffffffLL);
                unsigned ey = (unsigned)(ep >> 32);
                int A = tabg[ex * GD + dl];
                int B = tabg[ey * GD + dl];
                a_[u] = haddr(dl, max(A, B));
                w_[u] = w;
            }
#pragma unroll
            for (int u = 0; u < UE; ++u) {
                dedupe4(a_[u], w_[u], lane, pad);
                _Float16 v = H[a_[u]];
                H[a_[u]] = v + (_Float16)w_[u];
            }
        }
    }

    // ---- triangles: -w, max over 3 endpoints ----
    {
        int lo = (int)((long long)k2 * slice / SSL);
        int hi = (int)((long long)k2 * (slice + 1) / SSL);
        for (int s0 = lo + wv * 4 * UT; s0 < hi; s0 += NWV * 4 * UT) {
            int a_[UT];
            float w_[UT];
#pragma unroll
            for (int u = 0; u < UT; ++u) {
                int s = min(s0 + u * 4 + sub, hi - 1);
                bool act = (s0 + u * 4 + sub) < hi;
                unsigned i0 = (unsigned)tris[3 * s];
                unsigned i1 = (unsigned)tris[3 * s + 1];
                unsigned i2 = (unsigned)tris[3 * s + 2];
                float w = act ? -tw[s] : 0.f;
                int A = tabg[i0 * GD + dl];
                int B = tabg[i1 * GD + dl];
                int C = tabg[i2 * GD + dl];
                a_[u] = haddr(dl, max(A, max(B, C)));
                w_[u] = w;
            }
#pragma unroll
            for (int u = 0; u < UT; ++u) {
                dedupe4(a_[u], w_[u], lane, pad);
                _Float16 v = H[a_[u]];
                H[a_[u]] = v + (_Float16)w_[u];
            }
        }
    }

    __syncthreads();
    flush5(hist, g, out);
}

__global__ void wect_cumsum(float* __restrict__ out) {
    // one wave (64 lanes) per direction row of 256 floats
    int lane = threadIdx.x;
    float4* row = (float4*)out + (size_t)blockIdx.x * 64;
    float4 v = row[lane];
    v.y += v.x;
    v.z += v.y;
    v.w += v.z;
    float s = v.w;
    float mine = s;
    for (int off = 1; off < 64; off <<= 1) {
        float t = __shfl_up(s, off, 64);
        if (lane >= off) s += t;
    }
    float excl = s - mine;
    v.x += excl;
    v.y += excl;
    v.z += excl;
    v.w += excl;
    row[lane] = v;
}

// ---------------- fallback kernels (no workspace) ----------------

__global__ __launch_bounds__(512) void wect_simplex_rec(
    const int* __restrict__ edges, const float* __restrict__ ew,
    const int* __restrict__ tris, const float* __restrict__ tw, int k1, int k2,
    const float* __restrict__ vc, const float* __restrict__ dirs,
    const unsigned* __restrict__ maxbits, float* __restrict__ out) {
    __shared__ float hist[NBINS];
    for (int i = threadIdx.x; i < NBINS; i += blockDim.x) hist[i] = 0.f;
    int lane = threadIdx.x & 63;
    float d0 = dirs[lane * 3], d1 = dirs[lane * 3 + 1], d2 = dirs[lane * 3 + 2];
    float mh = __uint_as_float(*maxbits);
    float inv = 1.0f / (2.0f * mh);
    __syncthreads();
    int wid = (blockIdx.x * blockDim.x + threadIdx.x) >> 6;
    int nw = (gridDim.x * blockDim.x) >> 6;
    int total = k1 + k2;
    for (int s = wid; s < total; s += nw) {
        int idx;
        float w;
        if (s < k1) {
            int v0 = edges[2 * s], v1 = edges[2 * s + 1];
            float h0 = vc[3 * v0] * d0 + vc[3 * v0 + 1] * d1 + vc[3 * v0 + 2] * d2;
            float h1 = vc[3 * v1] * d0 + vc[3 * v1 + 1] * d1 + vc[3 * v1 + 2] * d2;
            idx = max(height_bin(h0, mh, inv), height_bin(h1, mh, inv));
            w = ew[s];
        } else {
            int t = s - k1;
            int v0 = tris[3 * t], v1 = tris[3 * t + 1], v2 = tris[3 * t + 2];
            float h0 = vc[3 * v0] * d0 + vc[3 * v0 + 1] * d1 + vc[3 * v0 + 2] * d2;
            float h1 = vc[3 * v1] * d0 + vc[3 * v1 + 1] * d1 + vc[3 * v1 + 2] * d2;
            float h2 = vc[3 * v2] * d0 + vc[3 * v2 + 1] * d1 + vc[3 * v2 + 2] * d2;
            idx = max(height_bin(h0, mh, inv),
                      max(height_bin(h1, mh, inv), height_bin(h2, mh, inv)));
            w = -tw[t];
        }
        atomicAdd(&hist[idx * NDIR + lane], w);
    }
    __syncthreads();
    for (int i = threadIdx.x; i < NBINS; i += blockDim.x) {
        float v = hist[i];
        if (v != 0.f) atomicAdd(&out[(i & 63) * HGT + (i >> 6)], v);
    }
}

__global__ __launch_bounds__(512) void wect_vertex_rec(
    const float* __restrict__ vc, const float* __restrict__ vw,
    const float* __restrict__ dirs, int k0,
    const unsigned* __restrict__ maxbits, float* __restrict__ out) {
    __shared__ float hist[NBINS];
    for (int i = threadIdx.x; i < NBINS; i += blockDim.x) hist[i] = 0.f;
    int lane = threadIdx.x & 63;
    float d0 = dirs[lane * 3], d1 = dirs[lane * 3 + 1], d2 = dirs[lane * 3 + 2];
    float mh = __uint_as_float(*maxbits);
    float inv = 1.0f / (2.0f * mh);
    __syncthreads();
    int wid = (blockIdx.x * blockDim.x + threadIdx.x) >> 6;
    int nw = (gridDim.x * blockDim.x) >> 6;
    for (int k = wid; k < k0; k += nw) {
        float h = vc[3 * k] * d0 + vc[3 * k + 1] * d1 + vc[3 * k + 2] * d2;
        int idx = height_bin(h, mh, inv);
        atomicAdd(&hist[idx * NDIR + lane], vw[k]);
    }
    __syncthreads();
    for (int i = threadIdx.x; i < NBINS; i += blockDim.x) {
        float v = hist[i];
        if (v != 0.f) atomicAdd(&out[(i & 63) * HGT + (i >> 6)], v);
    }
}

extern "C" void kernel_launch(void* const* d_in, const int* in_sizes, int n_in,
                              void* d_out, int out_size, void* d_ws,
                              size_t ws_size, hipStream_t stream) {
    const float* v_coords = (const float*)d_in[0];
    const float* v_weights = (const float*)d_in[1];
    const int* edges = (const int*)d_in[2];
    const float* e_weights = (const float*)d_in[3];
    const int* tris = (const int*)d_in[4];
    const float* t_weights = (const float*)d_in[5];
    const float* dirs = (const float*)d_in[6];
    // d_in[7] = num_heights (=256, hardcoded as HGT)

    int k0 = in_sizes[0] / 3;
    int k1 = in_sizes[2] / 2;
    int k2 = in_sizes[4] / 3;

    float* out = (float*)d_out;
    unsigned* maxbits = (unsigned*)d_ws;
    unsigned char* tab = (unsigned char*)d_ws + 64;
    bool have_table = ws_size >= 64 + (size_t)NG * k0 * GD;

    (void)hipMemsetAsync(d_ws, 0, 64, stream);
    (void)hipMemsetAsync(d_out, 0, (size_t)NBINS * sizeof(float), stream);

    wect_maxnorm<<<256, 256, 0, stream>>>(v_coords, k0, maxbits);

    if (have_table) {
        wect_vertex4<<<NG * VSL, TPB, 0, stream>>>(v_coords, v_weights, dirs,
                                                   k0, maxbits, tab, out);
        wect_simplex4<<<NG * SSL, TPB, 0, stream>>>(
            (const long long*)edges, e_weights, tris, t_weights, k1, k2, tab,
            k0, out);
    } else {
        wect_vertex_rec<<<512, 512, 0, stream>>>(v_coords, v_weights, dirs, k0,
                                                 maxbits, out);
        wect_simplex_rec<<<512, 512, 0, stream>>>(edges, e_weights, tris,
                                                  t_weights, k1, k2, v_coords,
                                                  dirs, maxbits, out);
    }
    wect_cumsum<<<NDIR, 64, 0, stream>>>(out);
}

// Round 18
// 218.926 us; speedup vs baseline: 1.8191x; 1.0230x over previous
//
#include <hip/hip_runtime.h>

// WECT R17 = R16 + compiler memory fences between masked RMW passes.
// R15/R16 failed with IDENTICAL absmax 4096 (fp16 AND exact-i16): the
// compiler legally merges `for ss { if(sub==ss) BODY }` (4 identical bodies,
// each lane executes exactly once) into ONE unguarded full-wave RMW ->
// duplicate addresses across sub-groups collide -> lost updates.
// Fix: asm volatile("":::"memory") after each pass = zero-instruction full
// compiler barrier; memory ops cannot move across it -> 4 truly separate
// exec-masked regions; hardware in-order LDS pipe makes them race-free.
// i16 fixed-point accumulation kept (exact; wq=round(w*32), RMS err ~10).
// Rest: GD=16, wave-private hist, U=2, TPB=192, 18 waves/CU, cached stream
// loads, per-group L2-pinned u8 tables, bin swizzle.

#define HGT 256
#define NDIR 64
#define NBINS (HGT * NDIR)
#define NG 4
#define GD 16
#define PADH16 258
#define WH16 (GD * PADH16)  // 4128 i16 per wave
#define TPB 192
#define NWV (TPB / 64)
#define VSL 384
#define SSL 384
#define UE 2
#define UT 2
#define UV 2
#define QSCALE 32.0f
#define QINV (1.0f / 32.0f)

__global__ void wect_maxnorm(const float* __restrict__ vc, int k0,
                             unsigned* __restrict__ maxbits) {
    float m = 0.f;
    for (int i = blockIdx.x * blockDim.x + threadIdx.x; i < k0;
         i += gridDim.x * blockDim.x) {
        float x = vc[3 * i], y = vc[3 * i + 1], z = vc[3 * i + 2];
        m = fmaxf(m, sqrtf(x * x + y * y + z * z));
    }
    for (int off = 32; off > 0; off >>= 1)
        m = fmaxf(m, __shfl_down(m, off, 64));
    __shared__ float sm[16];
    int wid = threadIdx.x >> 6, lane = threadIdx.x & 63;
    if (lane == 0) sm[wid] = m;
    __syncthreads();
    if (threadIdx.x == 0) {
        float b = sm[0];
        int nw = blockDim.x >> 6;
        for (int w = 1; w < nw; ++w) b = fmaxf(b, sm[w]);
        atomicMax(maxbits, __float_as_uint(b));  // valid: all values >= 0
    }
}

__device__ __forceinline__ int height_bin(float h, float mh, float inv) {
    int idx = (int)ceilf((255.0f * (mh + h)) * inv);
    return min(max(idx, 0), HGT - 1);
}

// i16-element offset inside a wave hist for (dir dl, bin b):
// swizzled so bins b and b+1 are 256B apart.
__device__ __forceinline__ int haddr(int dl, int b) {
    int p = ((b & 1) << 7) | (b >> 1);
    return dl * PADH16 + p;
}

__device__ __forceinline__ void flush6(const short* hist, int g,
                                       float* __restrict__ out) {
    for (int t = threadIdx.x; t < GD * HGT; t += TPB) {
        int d = t >> 8, b = t & 255;
        int p = d * PADH16 + (((b & 1) << 7) | (b >> 1));
        int s = 0;
#pragma unroll
        for (int u = 0; u < NWV; ++u) s += (int)hist[u * WH16 + p];
        if (s != 0) atomicAdd(&out[(g * GD + d) * HGT + b], (float)s * QINV);
    }
}

__global__ __launch_bounds__(TPB, 4) void wect_vertex4(
    const float* __restrict__ vc, const float* __restrict__ vw,
    const float* __restrict__ dirs, int k0,
    const unsigned* __restrict__ maxbits, unsigned char* __restrict__ tab,
    float* __restrict__ out) {
    __shared__ short hist[NWV * WH16];
    int tid = threadIdx.x, lane = tid & 63, wv = tid >> 6;
    int dl = lane & 15, sub = lane >> 4;
    for (int t = tid; t < NWV * WH16; t += TPB) hist[t] = 0;
    int g = blockIdx.x & (NG - 1);
    int slice = blockIdx.x >> 2;
    int gd = g * GD + dl;
    float dx = dirs[3 * gd], dy = dirs[3 * gd + 1], dz = dirs[3 * gd + 2];
    float mh = __uint_as_float(*maxbits);
    float inv = 1.0f / (2.0f * mh);
    unsigned char* tabg = tab + (size_t)g * ((size_t)k0 * GD);
    short* H = hist + wv * WH16;
    __syncthreads();
    int lo = (int)((long long)k0 * slice / VSL);
    int hi = (int)((long long)k0 * (slice + 1) / VSL);
    for (int s0 = lo + wv * 4 * UV; s0 < hi; s0 += NWV * 4 * UV) {
        int a_[UV];
        int q_[UV];
#pragma unroll
        for (int u = 0; u < UV; ++u) {
            int s = min(s0 + u * 4 + sub, hi - 1);
            bool act = (s0 + u * 4 + sub) < hi;
            float x = vc[3 * s], y = vc[3 * s + 1], z = vc[3 * s + 2];
            float w = act ? vw[s] : 0.f;
            float h = fmaf(x, dx, fmaf(y, dy, z * dz));
            int b = height_bin(h, mh, inv);
            if (act) tabg[(unsigned)s * GD + dl] = (unsigned char)b;
            a_[u] = haddr(dl, b);
            q_[u] = __float2int_rn(w * QSCALE);
        }
#pragma unroll
        for (int ss = 0; ss < 4; ++ss) {
            if (sub == ss) {
#pragma unroll
                for (int u = 0; u < UV; ++u) {
                    short v = H[a_[u]];
                    H[a_[u]] = (short)(v + q_[u]);
                }
            }
            asm volatile("" ::: "memory");  // forbid merging the 4 passes
        }
    }
    __syncthreads();
    flush6(hist, g, out);
}

__global__ __launch_bounds__(TPB, 4) void wect_simplex4(
    const long long* __restrict__ edges, const float* __restrict__ ew,
    const int* __restrict__ tris, const float* __restrict__ tw, int k1, int k2,
    const unsigned char* __restrict__ tab, int k0, float* __restrict__ out) {
    __shared__ short hist[NWV * WH16];
    int tid = threadIdx.x, lane = tid & 63, wv = tid >> 6;
    int dl = lane & 15, sub = lane >> 4;
    for (int t = tid; t < NWV * WH16; t += TPB) hist[t] = 0;
    int g = blockIdx.x & (NG - 1);
    int slice = blockIdx.x >> 2;
    const unsigned char* tabg = tab + (size_t)g * ((size_t)k0 * GD);
    short* H = hist + wv * WH16;
    __syncthreads();

    // ---- edges: +w, max over 2 endpoints ----
    {
        int lo = (int)((long long)k1 * slice / SSL);
        int hi = (int)((long long)k1 * (slice + 1) / SSL);
        for (int s0 = lo + wv * 4 * UE; s0 < hi; s0 += NWV * 4 * UE) {
            int a_[UE];
            int q_[UE];
#pragma unroll
            for (int u = 0; u < UE; ++u) {
                int s = min(s0 + u * 4 + sub, hi - 1);
                bool act = (s0 + u * 4 + sub) < hi;
                long long ep = edges[s];
                float w = act ? ew[s] : 0.f;
                unsigned ex = (unsigned)(ep & 0xffffffffLL);
                unsigned ey = (unsigned)(ep >> 32);
                int A = tabg[ex * GD + dl];
                int B = tabg[ey * GD + dl];
                a_[u] = haddr(dl, max(A, B));
                q_[u] = __float2int_rn(w * QSCALE);
            }
#pragma unroll
            for (int ss = 0; ss < 4; ++ss) {
                if (sub == ss) {
#pragma unroll
                    for (int u = 0; u < UE; ++u) {
                        short v = H[a_[u]];
                        H[a_[u]] = (short)(v + q_[u]);
                    }
                }
                asm volatile("" ::: "memory");  // forbid pass merging
            }
        }
    }

    // ---- triangles: -w, max over 3 endpoints ----
    {
        int lo = (int)((long long)k2 * slice / SSL);
        int hi = (int)((long long)k2 * (slice + 1) / SSL);
        for (int s0 = lo + wv * 4 * UT; s0 < hi; s0 += NWV * 4 * UT) {
            int a_[UT];
            int q_[UT];
#pragma unroll
            for (int u = 0; u < UT; ++u) {
                int s = min(s0 + u * 4 + sub, hi - 1);
                bool act = (s0 + u * 4 + sub) < hi;
                unsigned i0 = (unsigned)tris[3 * s];
                unsigned i1 = (unsigned)tris[3 * s + 1];
                unsigned i2 = (unsigned)tris[3 * s + 2];
                float w = act ? -tw[s] : 0.f;
                int A = tabg[i0 * GD + dl];
                int B = tabg[i1 * GD + dl];
                int C = tabg[i2 * GD + dl];
                a_[u] = haddr(dl, max(A, max(B, C)));
                q_[u] = __float2int_rn(w * QSCALE);
            }
#pragma unroll
            for (int ss = 0; ss < 4; ++ss) {
                if (sub == ss) {
#pragma unroll
                    for (int u = 0; u < UT; ++u) {
                        short v = H[a_[u]];
                        H[a_[u]] = (short)(v + q_[u]);
                    }
                }
                asm volatile("" ::: "memory");  // forbid pass merging
            }
        }
    }

    __syncthreads();
    flush6(hist, g, out);
}

__global__ void wect_cumsum(float* __restrict__ out) {
    // one wave (64 lanes) per direction row of 256 floats
    int lane = threadIdx.x;
    float4* row = (float4*)out + (size_t)blockIdx.x * 64;
    float4 v = row[lane];
    v.y += v.x;
    v.z += v.y;
    v.w += v.z;
    float s = v.w;
    float mine = s;
    for (int off = 1; off < 64; off <<= 1) {
        float t = __shfl_up(s, off, 64);
        if (lane >= off) s += t;
    }
    float excl = s - mine;
    v.x += excl;
    v.y += excl;
    v.z += excl;
    v.w += excl;
    row[lane] = v;
}

// ---------------- fallback kernels (no workspace) ----------------

__global__ __launch_bounds__(512) void wect_simplex_rec(
    const int* __restrict__ edges, const float* __restrict__ ew,
    const int* __restrict__ tris, const float* __restrict__ tw, int k1, int k2,
    const float* __restrict__ vc, const float* __restrict__ dirs,
    const unsigned* __restrict__ maxbits, float* __restrict__ out) {
    __shared__ float hist[NBINS];
    for (int i = threadIdx.x; i < NBINS; i += blockDim.x) hist[i] = 0.f;
    int lane = threadIdx.x & 63;
    float d0 = dirs[lane * 3], d1 = dirs[lane * 3 + 1], d2 = dirs[lane * 3 + 2];
    float mh = __uint_as_float(*maxbits);
    float inv = 1.0f / (2.0f * mh);
    __syncthreads();
    int wid = (blockIdx.x * blockDim.x + threadIdx.x) >> 6;
    int nw = (gridDim.x * blockDim.x) >> 6;
    int total = k1 + k2;
    for (int s = wid; s < total; s += nw) {
        int idx;
        float w;
        if (s < k1) {
            int v0 = edges[2 * s], v1 = edges[2 * s + 1];
            float h0 = vc[3 * v0] * d0 + vc[3 * v0 + 1] * d1 + vc[3 * v0 + 2] * d2;
            float h1 = vc[3 * v1] * d0 + vc[3 * v1 + 1] * d1 + vc[3 * v1 + 2] * d2;
            idx = max(height_bin(h0, mh, inv), height_bin(h1, mh, inv));
            w = ew[s];
        } else {
            int t = s - k1;
            int v0 = tris[3 * t], v1 = tris[3 * t + 1], v2 = tris[3 * t + 2];
            float h0 = vc[3 * v0] * d0 + vc[3 * v0 + 1] * d1 + vc[3 * v0 + 2] * d2;
            float h1 = vc[3 * v1] * d0 + vc[3 * v1 + 1] * d1 + vc[3 * v1 + 2] * d2;
            float h2 = vc[3 * v2] * d0 + vc[3 * v2 + 1] * d1 + vc[3 * v2 + 2] * d2;
            idx = max(height_bin(h0, mh, inv),
                      max(height_bin(h1, mh, inv), height_bin(h2, mh, inv)));
            w = -tw[t];
        }
        atomicAdd(&hist[idx * NDIR + lane], w);
    }
    __syncthreads();
    for (int i = threadIdx.x; i < NBINS; i += blockDim.x) {
        float v = hist[i];
        if (v != 0.f) atomicAdd(&out[(i & 63) * HGT + (i >> 6)], v);
    }
}

__global__ __launch_bounds__(512) void wect_vertex_rec(
    const float* __restrict__ vc, const float* __restrict__ vw,
    const float* __restrict__ dirs, int k0,
    const unsigned* __restrict__ maxbits, float* __restrict__ out) {
    __shared__ float hist[NBINS];
    for (int i = threadIdx.x; i < NBINS; i += blockDim.x) hist[i] = 0.f;
    int lane = threadIdx.x & 63;
    float d0 = dirs[lane * 3], d1 = dirs[lane * 3 + 1], d2 = dirs[lane * 3 + 2];
    float mh = __uint_as_float(*maxbits);
    float inv = 1.0f / (2.0f * mh);
    __syncthreads();
    int wid = (blockIdx.x * blockDim.x + threadIdx.x) >> 6;
    int nw = (gridDim.x * blockDim.x) >> 6;
    for (int k = wid; k < k0; k += nw) {
        float h = vc[3 * k] * d0 + vc[3 * k + 1] * d1 + vc[3 * k + 2] * d2;
        int idx = height_bin(h, mh, inv);
        atomicAdd(&hist[idx * NDIR + lane], vw[k]);
    }
    __syncthreads();
    for (int i = threadIdx.x; i < NBINS; i += blockDim.x) {
        float v = hist[i];
        if (v != 0.f) atomicAdd(&out[(i & 63) * HGT + (i >> 6)], v);
    }
}

extern "C" void kernel_launch(void* const* d_in, const int* in_sizes, int n_in,
                              void* d_out, int out_size, void* d_ws,
                              size_t ws_size, hipStream_t stream) {
    const float* v_coords = (const float*)d_in[0];
    const float* v_weights = (const float*)d_in[1];
    const int* edges = (const int*)d_in[2];
    const float* e_weights = (const float*)d_in[3];
    const int* tris = (const int*)d_in[4];
    const float* t_weights = (const float*)d_in[5];
    const float* dirs = (const float*)d_in[6];
    // d_in[7] = num_heights (=256, hardcoded as HGT)

    int k0 = in_sizes[0] / 3;
    int k1 = in_sizes[2] / 2;
    int k2 = in_sizes[4] / 3;

    float* out = (float*)d_out;
    unsigned* maxbits = (unsigned*)d_ws;
    unsigned char* tab = (unsigned char*)d_ws + 64;
    bool have_table = ws_size >= 64 + (size_t)NG * k0 * GD;

    (void)hipMemsetAsync(d_ws, 0, 64, stream);
    (void)hipMemsetAsync(d_out, 0, (size_t)NBINS * sizeof(float), stream);

    wect_maxnorm<<<256, 256, 0, stream>>>(v_coords, k0, maxbits);

    if (have_table) {
        wect_vertex4<<<NG * VSL, TPB, 0, stream>>>(v_coords, v_weights, dirs,
                                                   k0, maxbits, tab, out);
        wect_simplex4<<<NG * SSL, TPB, 0, stream>>>(
            (const long long*)edges, e_weights, tris, t_weights, k1, k2, tab,
            k0, out);
    } else {
        wect_vertex_rec<<<512, 512, 0, stream>>>(v_coords, v_weights, dirs, k0,
                                                 maxbits, out);
        wect_simplex_rec<<<512, 512, 0, stream>>>(edges, e_weights, tris,
                                                  t_weights, k1, k2, v_coords,
                                                  dirs, maxbits, out);
    }
    wect_cumsum<<<NDIR, 64, 0, stream>>>(out);
}